// Round 22
// baseline (7752.636 us; speedup 1.0000x reference)
//
#include <hip/hip_runtime.h>
#include <cmath>

#define TT 512
#define BB 64
#define HH 512
#define II 128
#define NBLK 256

typedef float v2f __attribute__((ext_vector_type(2)));
__device__ __forceinline__ v2f fma2(v2f a, v2f b, v2f c) { return __builtin_elementwise_fma(a, b, c); }

// dynamic LDS floats: wlds 16*1024 =16384 | part 16*16*32*2 =16384 |
// gates 16*64 =1024 | cst 256 | bsum 16   => ~133 KB  (=> 1 block/CU)
#define SMEM_FLOATS (16384 + 16384 + 1024 + 256 + 16)
#define SMEM_BYTES  (SMEM_FLOATS * 4)

// fast transcendentals (r18/r20/r21-proven: absmax 0.0 with these)
__device__ __forceinline__ float fexp2(float x) { float r; asm("v_exp_f32 %0, %1" : "=v"(r) : "v"(x)); return r; }
__device__ __forceinline__ float frcpf(float x) { float r; asm("v_rcp_f32 %0, %1" : "=v"(r) : "v"(x)); return r; }
__device__ __forceinline__ float sigm(float v)  { return frcpf(1.0f + fexp2(-1.44269504f * v)); }
__device__ __forceinline__ float ftanh(float v) { return __builtin_fmaf(2.0f, frcpf(1.0f + fexp2(-2.88539008f * v)), -1.0f); }

__device__ __forceinline__ unsigned umin2(unsigned a, unsigned b) { return a < b ? a : b; }
#define CBAR() asm volatile("" ::: "memory")   // compiler-only reorder fence

// 8-byte bypass (relaxed AGENT atomic) load of a batch-pair of h.
// Served from the coherence point — immune to stale local lines (r13-proven).
__device__ __forceinline__ v2f loadh2(const float* p) {
  unsigned long long r = __hip_atomic_load((const unsigned long long*)p,
                                           __ATOMIC_RELAXED, __HIP_MEMORY_SCOPE_AGENT);
  v2f v;
  v.x = __uint_as_float((unsigned)r);
  v.y = __uint_as_float((unsigned)(r >> 32));
  return v;
}
template<int KN>
__device__ __forceinline__ void loadh2b(const float* __restrict__ src, int k0,
                                        int bp, v2f (&v)[KN]) {
#pragma unroll
  for (int i = 0; i < KN; ++i) v[i] = loadh2(src + (size_t)(k0 + i) * BB + 2 * bp);
}
// x: plain cached 8B loads (immutable input, L2-resident).
template<int KN>
__device__ __forceinline__ void loadx2(const float* __restrict__ src, int k0,
                                       int bp, v2f (&v)[KN]) {
#pragma unroll
  for (int i = 0; i < KN; ++i)
    v[i] = *(const v2f*)(src + (size_t)(k0 + i) * BB + 2 * bp);
}

// One k for THIS lane's row-half (8 rows): 2 ds_read_b128 (2-address across
// the wave -> free 2-way) + 8 v_pk_fma over the lane's batch-pair.
__device__ __forceinline__ void step2(const float* wk8, v2f h2, v2f (&acc)[8]) {
  const float4* wp = (const float4*)wk8;
  const float4 w0 = wp[0], w1 = wp[1];
  acc[0] = fma2((v2f){w0.x, w0.x}, h2, acc[0]);
  acc[1] = fma2((v2f){w0.y, w0.y}, h2, acc[1]);
  acc[2] = fma2((v2f){w0.z, w0.z}, h2, acc[2]);
  acc[3] = fma2((v2f){w0.w, w0.w}, h2, acc[3]);
  acc[4] = fma2((v2f){w1.x, w1.x}, h2, acc[4]);
  acc[5] = fma2((v2f){w1.y, w1.y}, h2, acc[5]);
  acc[6] = fma2((v2f){w1.z, w1.z}, h2, acc[6]);
  acc[7] = fma2((v2f){w1.w, w1.w}, h2, acc[7]);
}
template<int KN>
__device__ __forceinline__ void consume2(const float* __restrict__ wro, int k0,
                                         const v2f (&v)[KN], v2f (&acc)[8]) {
#pragma unroll
  for (int i = 0; i < KN; ++i) step2(wro + (size_t)(k0 + i) * 16, v[i], acc);
}

// FUSED pipeline over NBA batches from (srcA,wroA) then NBB from (srcB,wroB):
// one continuous 2-deep ping-pong — the source switch at batch NBA crosses
// seamlessly, removing the exposed inter-span MALL round trip r21 paid.
// Staging = 8 v2f (same as r21's span32: no added register pressure).
template<int NBA, int NBB>
__device__ __forceinline__ void span_fused(
    const float* __restrict__ srcA, const float* __restrict__ wroA_,
    const float* __restrict__ srcB, const float* __restrict__ wroB_,
    int k0A, int k0B, int bp, v2f (&acc)[8]) {
  constexpr int NB = NBA + NBB;
  v2f bufa[4], bufb[4];
  // load batch j into buf
  auto LD = [&](int j, v2f (&buf)[4]) {
    const float* src = (j < NBA) ? srcA : srcB;
    const int kk = (j < NBA) ? (k0A + 4 * j) : (k0B + 4 * (j - NBA));
    loadh2b<4>(src, kk, bp, buf);
  };
  auto CO = [&](int j, v2f (&buf)[4]) {
    const float* wro = (j < NBA) ? wroA_ : wroB_;
    const int kk = (j < NBA) ? (k0A + 4 * j) : (k0B + 4 * (j - NBA));
    consume2<4>(wro, kk, buf, acc);
  };
  LD(0, bufa);
  if (NB > 1) LD(1, bufb);
#pragma unroll
  for (int j = 0; j < NB; ++j) {
    if ((j & 1) == 0) { CO(j, bufa); if (j + 2 < NB) LD(j + 2, bufa); }
    else              { CO(j, bufb); if (j + 2 < NB) LD(j + 2, bufb); }
  }
}

// ---------------------------------------------------------------------------
// Transpose x: [64][512][128] (b,t,k) -> xT: [512][128][64] (t,k,b)
// ---------------------------------------------------------------------------
__global__ __launch_bounds__(1024) void k_transpose_x(const float* __restrict__ x,
                                                      float* __restrict__ xT) {
  __shared__ float tile[64][65];
  const int t  = blockIdx.x >> 1;
  const int k0 = (blockIdx.x & 1) << 6;
  const int lk = threadIdx.x & 63;
  const int lb = threadIdx.x >> 6;
#pragma unroll
  for (int bp = 0; bp < 64; bp += 16) {
    const int b = bp + lb;
    tile[lk][b] = x[((size_t)b * TT + t) * II + k0 + lk];
  }
  __syncthreads();
  const int b2  = threadIdx.x & 63;
  const int kk0 = threadIdx.x >> 6;
#pragma unroll
  for (int kp = 0; kp < 64; kp += 16) {
    const int kk = kp + kk0;
    xT[((size_t)t * II + k0 + kk) * BB + b2] = tile[kk][b2];
  }
}

__global__ void k_init_flags(unsigned* flags) { flags[threadIdx.x] = 0u; }

// ---------------------------------------------------------------------------
// Persistent pipelined 2-layer LSTM — r21 base (7.00ms) + two latency cuts:
//  (1) ALL-WAVE SPIN: every wave polls the u64-packed flags independently and
//      proceeds on its own detection — the post-spin __syncthreads (barrier-
//      release latency on the critical path every phase) is GONE. Safe: the
//      pre-publish barrier already means flags>=s implies every wave of every
//      block finished phase s-1; each wave's h loads issue after its own flag
//      observation (same MALL ordering argument as r13).
//  (2) FUSED L1 pipeline: h0-span + h1-span run as one 16-batch ping-pong —
//      removes the exposed inter-span MALL round trip.
// Protocol (proven r13..r21): swap-with-return publish -> barrier -> relaxed
// flag; consumer = relaxed spin + bypass atomic h loads (no fences at all).
// ---------------------------------------------------------------------------
__global__ __launch_bounds__(1024, 4) void k_lstm_persist(
    const float* __restrict__ xT,
    const float* __restrict__ W_ih0, const float* __restrict__ W_hh0,
    const float* __restrict__ b_ih0, const float* __restrict__ b_hh0,
    const float* __restrict__ W_ih1, const float* __restrict__ W_hh1,
    const float* __restrict__ b_ih1, const float* __restrict__ b_hh1,
    float* __restrict__ h0ring, float* __restrict__ h1ring,
    unsigned* __restrict__ flags)
{
  extern __shared__ float smem[];
  float* wlds  = smem;            // [k up to 1024][16 rows] k-major
  float* part  = wlds + 16384;    // [row16][kseg16][bp32][2]
  float* gates = part + 16384;    // [row16][b64]  (ACTIVATED values)
  float* cst   = gates + 1024;    // [u4][b64]
  float* bsum  = cst + 256;       // [16]

  const int bid = blockIdx.x;
  const int L   = bid >> 7;
  const int ub  = (bid & 127) << 2;   // 4 hidden units per block
  const int tid = threadIdx.x;

  const float* WA = L ? W_ih1 : W_ih0;
  const float* WB = L ? W_hh1 : W_hh0;
  const int KA = L ? HH : II;

  // ---- one-time: stage weights k-major + bias sums + c=0 ----
  const int ktot = KA + HH;
  for (int idx = tid; idx < 16 * ktot; idx += 1024) {
    const int k  = idx >> 4;
    const int lr = idx & 15;
    const int u = lr >> 2, q = lr & 3;
    const int G = q * HH + ub + u;           // i,f,g,o chunk order
    wlds[idx] = (k < KA) ? WA[G * KA + k] : WB[G * HH + (k - KA)];
  }
  if (tid < 16) {
    const int u = tid >> 2, q = tid & 3;
    const int G = q * HH + ub + u;
    bsum[tid] = L ? (b_ih1[G] + b_hh1[G]) : (b_ih0[G] + b_hh0[G]);
  }
  if (tid < 256) cst[tid] = 0.0f;
  __syncthreads();

  const int lane  = tid & 63;
  const int bp    = tid & 31;         // batch-pair index (b = 2bp, 2bp+1)
  const int rhalf = (tid >> 5) & 1;   // row half (0..7 / 8..15)
  const int kseg  = tid >> 6;         // 0..15

  const float* wroA  = wlds + rhalf * 8;                    // A-operand rows
  const float* wroB0 = wlds + (size_t)II * 16 + rhalf * 8;  // L0 B rows
  const float* wroB1 = wlds + (size_t)HH * 16 + rhalf * 8;  // L1 B rows

  for (int s = 0; s <= TT; ++s) {
    const int t = L ? (s - 1) : s;
    const bool active = (t >= 0 && t < TT);
    const bool first  = (t == 0);

    v2f acc[8];
#pragma unroll
    for (int j = 0; j < 8; ++j) acc[j] = (v2f){0.0f, 0.0f};

    // ---- L0: load AND consume the x-part BEFORE the wait (local data) ----
    if (active && L == 0) {
      v2f xa[4], xb[4];
      const float* xp = xT + (size_t)t * (II * BB);
      loadx2<4>(xp, kseg * 8,     bp, xa);
      loadx2<4>(xp, kseg * 8 + 4, bp, xb);
      consume2<4>(wroA, kseg * 8,     xa, acc);
      consume2<4>(wroA, kseg * 8 + 4, xb, acc);
    }

    // ---- wait: ALL WAVES spin independently (no post-spin barrier) ----
    if (s > 0) {
      const unsigned tgt = (unsigned)s;
      const unsigned long long* f64 = (const unsigned long long*)flags;
      for (;;) {
        const unsigned long long a = __hip_atomic_load(f64 + lane,      __ATOMIC_RELAXED, __HIP_MEMORY_SCOPE_AGENT);
        const unsigned long long b = __hip_atomic_load(f64 + lane + 64, __ATOMIC_RELAXED, __HIP_MEMORY_SCOPE_AGENT);
        const unsigned mn = umin2(umin2((unsigned)a, (unsigned)(a >> 32)),
                                  umin2((unsigned)b, (unsigned)(b >> 32)));
        if (__all(mn >= tgt)) break;
        __builtin_amdgcn_s_sleep(1);
      }
      CBAR();   // keep h loads below the spin at IR level
    }

    if (active) {
      if (L == 0) {
        if (!first) {  // B-part: h0[s-1] @ parity (s-1)&1
          span_fused<8, 0>(h0ring + (size_t)((s - 1) & 1) * (HH * BB), wroB0,
                           nullptr, nullptr, kseg * 32, 0, bp, acc);
        }
      } else {
        const float* h0src = h0ring + (size_t)((s - 1) & 1) * (HH * BB);
        if (first) {
          span_fused<8, 0>(h0src, wroA, nullptr, nullptr,
                           kseg * 32, 0, bp, acc);
        } else {  // fused: h0[s-1] (A) then h1[s-2] (B), one pipeline
          span_fused<8, 8>(h0src, wroA,
                           h1ring + (size_t)(s & 1) * (HH * BB), wroB1,
                           kseg * 32, kseg * 32, bp, acc);
        }
      }

      // ---- reduce 16 ksegs -> ACTIVATED gates (16-wave parallel) ----
#pragma unroll
      for (int j = 0; j < 8; ++j) {
        const int row = rhalf * 8 + j;
        *(v2f*)(part + ((((size_t)row * 16 + kseg) * 32 + bp) << 1)) = acc[j];
      }
      __syncthreads();
      {
        const int row = tid >> 6;       // = lr = u*4 + q
        const int bb  = tid & 63;
        const int q   = row & 3;
        float g = 0.0f;
#pragma unroll
        for (int ks = 0; ks < 16; ++ks)
          g += part[((((size_t)row * 16 + ks) * 32 + (bb >> 1)) << 1) + (bb & 1)];
        g += bsum[row];
        gates[row * 64 + bb] = (q == 2) ? ftanh(g) : sigm(g);
      }
      __syncthreads();

      if (tid < 128) {  // cell update: 2 batch elems/thread, 64-bit swap
        const int u   = tid >> 5;
        const int bb0 = (tid & 31) << 1, bb1 = bb0 + 1;
        const float gi0 = gates[((u << 2) + 0) * 64 + bb0];
        const float gf0 = gates[((u << 2) + 1) * 64 + bb0];
        const float gg0 = gates[((u << 2) + 2) * 64 + bb0];
        const float go0 = gates[((u << 2) + 3) * 64 + bb0];
        const float gi1 = gates[((u << 2) + 0) * 64 + bb1];
        const float gf1 = gates[((u << 2) + 1) * 64 + bb1];
        const float gg1 = gates[((u << 2) + 2) * 64 + bb1];
        const float go1 = gates[((u << 2) + 3) * 64 + bb1];
        const float c0 = first ? 0.0f : cst[u * 64 + bb0];
        const float c1 = first ? 0.0f : cst[u * 64 + bb1];
        const float cn0 = gf0 * c0 + gi0 * gg0;
        const float cn1 = gf1 * c1 + gi1 * gg1;
        const float hn0 = go0 * ftanh(cn0);
        const float hn1 = go1 * ftanh(cn1);
        cst[u * 64 + bb0] = cn0;
        cst[u * 64 + bb1] = cn1;
        float* hdst = (L ? h1ring : h0ring) + (size_t)(t & 1) * (HH * BB);
        unsigned long long pk =
            (unsigned long long)__float_as_uint(hn0) |
            ((unsigned long long)__float_as_uint(hn1) << 32);
        // 64-bit swap-with-return: performed AT the MALL; asm sink forces
        // the s_waitcnt on the return before the barrier below (r16-proven).
        unsigned long long old = __hip_atomic_exchange(
            (unsigned long long*)(hdst + (ub + u) * 64 + bb0), pk,
            __ATOMIC_RELAXED, __HIP_MEMORY_SCOPE_AGENT);
        asm volatile("" :: "v"(old));
      }
    }

    // all swaps' returns received (h at MALL) before any thread passes here;
    // the flag store is issued strictly afterwards -> cannot be seen early.
    __syncthreads();
    if (tid == 0 && s < TT) {   // last phase: nobody consumes the flag
      __hip_atomic_store(flags + bid, (unsigned)(s + 1),
                         __ATOMIC_RELAXED, __HIP_MEMORY_SCOPE_AGENT);
    }
  }
}

// ---------------------------------------------------------------------------
// out[b] = sum_j h1_last[j][b] * Wl[j] + bl[0]
// ---------------------------------------------------------------------------
__global__ __launch_bounds__(512) void k_final(const float* __restrict__ h1last,
                                               const float* __restrict__ Wl,
                                               const float* __restrict__ bl,
                                               float* __restrict__ out) {
  __shared__ float red[8][64];
  const int jg = threadIdx.x >> 6, b = threadIdx.x & 63;
  float a = 0.0f;
  for (int jj = 0; jj < 64; ++jj) {
    const int j = (jg << 6) + jj;
    a += h1last[j * BB + b] * Wl[j];
  }
  red[jg][b] = a;
  __syncthreads();
  if (threadIdx.x < 64) {
    float s = bl[0];
#pragma unroll
    for (int g = 0; g < 8; ++g) s += red[g][threadIdx.x];
    out[threadIdx.x] = s;
  }
}

extern "C" void kernel_launch(void* const* d_in, const int* in_sizes, int n_in,
                              void* d_out, int out_size, void* d_ws, size_t ws_size,
                              hipStream_t stream) {
  (void)in_sizes; (void)n_in; (void)out_size; (void)ws_size;
  const float* x     = (const float*)d_in[0];
  const float* W_ih0 = (const float*)d_in[1];
  const float* W_hh0 = (const float*)d_in[2];
  const float* b_ih0 = (const float*)d_in[3];
  const float* b_hh0 = (const float*)d_in[4];
  const float* W_ih1 = (const float*)d_in[5];
  const float* W_hh1 = (const float*)d_in[6];
  const float* b_ih1 = (const float*)d_in[7];
  const float* b_hh1 = (const float*)d_in[8];
  const float* Wl    = (const float*)d_in[9];
  const float* bl    = (const float*)d_in[10];
  float* out = (float*)d_out;

  float* ws       = (float*)d_ws;
  float* xT       = ws;                         // 512*128*64
  float* h0ring   = xT + (size_t)TT * II * BB;  // 2*512*64
  float* h1ring   = h0ring + 2 * HH * BB;       // 2*512*64
  unsigned* flags = (unsigned*)(h1ring + 2 * HH * BB);  // 256 u32 (8B aligned)

  k_transpose_x<<<1024, 1024, 0, stream>>>(x, xT);
  k_init_flags<<<1, NBLK, 0, stream>>>(flags);

  hipFuncSetAttribute((const void*)k_lstm_persist,
                      hipFuncAttributeMaxDynamicSharedMemorySize, SMEM_BYTES);

  void* args[] = {
    (void*)&xT,
    (void*)&W_ih0, (void*)&W_hh0, (void*)&b_ih0, (void*)&b_hh0,
    (void*)&W_ih1, (void*)&W_hh1, (void*)&b_ih1, (void*)&b_hh1,
    (void*)&h0ring, (void*)&h1ring, (void*)&flags,
  };
  // Cooperative launch kept ONLY for the co-residency guarantee; sync is ours.
  hipLaunchCooperativeKernel((void*)k_lstm_persist, dim3(NBLK), dim3(1024),
                             args, SMEM_BYTES, stream);

  // h1[T-1] lives at ring parity (T-1)&1 == 1
  k_final<<<1, 512, 0, stream>>>(h1ring + HH * BB, Wl, bl, out);
}

// Round 23
// 6905.025 us; speedup vs baseline: 1.1228x; 1.1228x over previous
//
#include <hip/hip_runtime.h>
#include <cmath>

#define TT 512
#define BB 64
#define HH 512
#define II 128
#define NBLK 256

typedef float v2f __attribute__((ext_vector_type(2)));
__device__ __forceinline__ v2f fma2(v2f a, v2f b, v2f c) { return __builtin_elementwise_fma(a, b, c); }

// dynamic LDS floats: wlds 16*1024 =16384 | part 16*16*32*2 =16384 |
// gates 16*64 =1024 | cst 256 | bsum 16   => ~133 KB  (=> 1 block/CU)
#define SMEM_FLOATS (16384 + 16384 + 1024 + 256 + 16)
#define SMEM_BYTES  (SMEM_FLOATS * 4)

// fast transcendentals (r18/r20/r21-proven: absmax 0.0 with these)
__device__ __forceinline__ float fexp2(float x) { float r; asm("v_exp_f32 %0, %1" : "=v"(r) : "v"(x)); return r; }
__device__ __forceinline__ float frcpf(float x) { float r; asm("v_rcp_f32 %0, %1" : "=v"(r) : "v"(x)); return r; }
__device__ __forceinline__ float sigm(float v)  { return frcpf(1.0f + fexp2(-1.44269504f * v)); }
__device__ __forceinline__ float ftanh(float v) { return __builtin_fmaf(2.0f, frcpf(1.0f + fexp2(-2.88539008f * v)), -1.0f); }

__device__ __forceinline__ unsigned umin2(unsigned a, unsigned b) { return a < b ? a : b; }
#define CBAR() asm volatile("" ::: "memory")   // compiler-only reorder fence

// 8-byte bypass (relaxed AGENT atomic) load of a batch-pair of h.
// Served from the coherence point — immune to stale local lines (r13-proven).
__device__ __forceinline__ v2f loadh2(const float* p) {
  unsigned long long r = __hip_atomic_load((const unsigned long long*)p,
                                           __ATOMIC_RELAXED, __HIP_MEMORY_SCOPE_AGENT);
  v2f v;
  v.x = __uint_as_float((unsigned)r);
  v.y = __uint_as_float((unsigned)(r >> 32));
  return v;
}
template<int KN>
__device__ __forceinline__ void loadh2b(const float* __restrict__ src, int k0,
                                        int bp, v2f (&v)[KN]) {
#pragma unroll
  for (int i = 0; i < KN; ++i) v[i] = loadh2(src + (size_t)(k0 + i) * BB + 2 * bp);
}
// x: plain cached 8B loads (immutable input, L2-resident).
template<int KN>
__device__ __forceinline__ void loadx2(const float* __restrict__ src, int k0,
                                       int bp, v2f (&v)[KN]) {
#pragma unroll
  for (int i = 0; i < KN; ++i)
    v[i] = *(const v2f*)(src + (size_t)(k0 + i) * BB + 2 * bp);
}

// One k for THIS lane's row-half (8 rows): 2 ds_read_b128 (2-address across
// the wave -> free 2-way) + 8 v_pk_fma over the lane's batch-pair.
__device__ __forceinline__ void step2(const float* wk8, v2f h2, v2f (&acc)[8]) {
  const float4* wp = (const float4*)wk8;
  const float4 w0 = wp[0], w1 = wp[1];
  acc[0] = fma2((v2f){w0.x, w0.x}, h2, acc[0]);
  acc[1] = fma2((v2f){w0.y, w0.y}, h2, acc[1]);
  acc[2] = fma2((v2f){w0.z, w0.z}, h2, acc[2]);
  acc[3] = fma2((v2f){w0.w, w0.w}, h2, acc[3]);
  acc[4] = fma2((v2f){w1.x, w1.x}, h2, acc[4]);
  acc[5] = fma2((v2f){w1.y, w1.y}, h2, acc[5]);
  acc[6] = fma2((v2f){w1.z, w1.z}, h2, acc[6]);
  acc[7] = fma2((v2f){w1.w, w1.w}, h2, acc[7]);
}
template<int KN>
__device__ __forceinline__ void consume2(const float* __restrict__ wro, int k0,
                                         const v2f (&v)[KN], v2f (&acc)[8]) {
#pragma unroll
  for (int i = 0; i < KN; ++i) step2(wro + (size_t)(k0 + i) * 16, v[i], acc);
}

// 32-k span, 4-deep ping-pong (8 v2f staging = 16 VGPRs -> no spills).
__device__ __forceinline__ void span32(const float* __restrict__ src,
                                       const float* __restrict__ wro,
                                       int k0, int bp, v2f (&acc)[8]) {
  v2f a[4], b[4];
  loadh2b<4>(src, k0,      bp, a);
  loadh2b<4>(src, k0 + 4,  bp, b);
  consume2<4>(wro, k0,      a, acc);
  loadh2b<4>(src, k0 + 8,  bp, a);
  consume2<4>(wro, k0 + 4,  b, acc);
  loadh2b<4>(src, k0 + 12, bp, b);
  consume2<4>(wro, k0 + 8,  a, acc);
  loadh2b<4>(src, k0 + 16, bp, a);
  consume2<4>(wro, k0 + 12, b, acc);
  loadh2b<4>(src, k0 + 20, bp, b);
  consume2<4>(wro, k0 + 16, a, acc);
  loadh2b<4>(src, k0 + 24, bp, a);
  consume2<4>(wro, k0 + 20, b, acc);
  loadh2b<4>(src, k0 + 28, bp, b);
  consume2<4>(wro, k0 + 24, a, acc);
  consume2<4>(wro, k0 + 28, b, acc);
}

// ---------------------------------------------------------------------------
// Transpose x: [64][512][128] (b,t,k) -> xT: [512][128][64] (t,k,b)
// ---------------------------------------------------------------------------
__global__ __launch_bounds__(1024) void k_transpose_x(const float* __restrict__ x,
                                                      float* __restrict__ xT) {
  __shared__ float tile[64][65];
  const int t  = blockIdx.x >> 1;
  const int k0 = (blockIdx.x & 1) << 6;
  const int lk = threadIdx.x & 63;
  const int lb = threadIdx.x >> 6;
#pragma unroll
  for (int bp = 0; bp < 64; bp += 16) {
    const int b = bp + lb;
    tile[lk][b] = x[((size_t)b * TT + t) * II + k0 + lk];
  }
  __syncthreads();
  const int b2  = threadIdx.x & 63;
  const int kk0 = threadIdx.x >> 6;
#pragma unroll
  for (int kp = 0; kp < 64; kp += 16) {
    const int kk = kp + kk0;
    xT[((size_t)t * II + k0 + kk) * BB + b2] = tile[kk][b2];
  }
}

__global__ void k_init_flags(unsigned* flags) { flags[threadIdx.x] = 0u; }

// ---------------------------------------------------------------------------
// Persistent pipelined 2-layer LSTM — r21 configuration (best: 7.00 ms),
// restored verbatim after r22's all-wave-spin regression (16x flag-poll MALL
// traffic slowed the shared coherence point; one polling wave per block is
// the right balance).
//  (1) 64-bit packed h swaps (r16-proven): 128 publish ops/block, not 256.
//  (2) activations fused into the 16-wave reduce stage (cell tail shrinks).
//  (3) u64-packed wave-0 flag spin: 2 bypass loads/lane instead of 4.
//  (4) dead last-phase flag store skipped; fast v_exp/v_rcp transcendentals.
// Protocol (proven r13..r21): swap-with-return publish -> barrier -> relaxed
// flag; consumer = relaxed spin + bypass atomic h loads (no fences at all).
// ---------------------------------------------------------------------------
__global__ __launch_bounds__(1024, 4) void k_lstm_persist(
    const float* __restrict__ xT,
    const float* __restrict__ W_ih0, const float* __restrict__ W_hh0,
    const float* __restrict__ b_ih0, const float* __restrict__ b_hh0,
    const float* __restrict__ W_ih1, const float* __restrict__ W_hh1,
    const float* __restrict__ b_ih1, const float* __restrict__ b_hh1,
    float* __restrict__ h0ring, float* __restrict__ h1ring,
    unsigned* __restrict__ flags)
{
  extern __shared__ float smem[];
  float* wlds  = smem;            // [k up to 1024][16 rows] k-major
  float* part  = wlds + 16384;    // [row16][kseg16][bp32][2]
  float* gates = part + 16384;    // [row16][b64]  (ACTIVATED values)
  float* cst   = gates + 1024;    // [u4][b64]
  float* bsum  = cst + 256;       // [16]

  const int bid = blockIdx.x;
  const int L   = bid >> 7;
  const int ub  = (bid & 127) << 2;   // 4 hidden units per block
  const int tid = threadIdx.x;

  const float* WA = L ? W_ih1 : W_ih0;
  const float* WB = L ? W_hh1 : W_hh0;
  const int KA = L ? HH : II;

  // ---- one-time: stage weights k-major + bias sums + c=0 ----
  const int ktot = KA + HH;
  for (int idx = tid; idx < 16 * ktot; idx += 1024) {
    const int k  = idx >> 4;
    const int lr = idx & 15;
    const int u = lr >> 2, q = lr & 3;
    const int G = q * HH + ub + u;           // i,f,g,o chunk order
    wlds[idx] = (k < KA) ? WA[G * KA + k] : WB[G * HH + (k - KA)];
  }
  if (tid < 16) {
    const int u = tid >> 2, q = tid & 3;
    const int G = q * HH + ub + u;
    bsum[tid] = L ? (b_ih1[G] + b_hh1[G]) : (b_ih0[G] + b_hh0[G]);
  }
  if (tid < 256) cst[tid] = 0.0f;
  __syncthreads();

  const int bp    = tid & 31;         // batch-pair index (b = 2bp, 2bp+1)
  const int rhalf = (tid >> 5) & 1;   // row half (0..7 / 8..15)
  const int kseg  = tid >> 6;         // 0..15

  const float* wroA  = wlds + rhalf * 8;                    // A-operand rows
  const float* wroB0 = wlds + (size_t)II * 16 + rhalf * 8;  // L0 B rows
  const float* wroB1 = wlds + (size_t)HH * 16 + rhalf * 8;  // L1 B rows

  for (int s = 0; s <= TT; ++s) {
    const int t = L ? (s - 1) : s;
    const bool active = (t >= 0 && t < TT);
    const bool first  = (t == 0);

    v2f acc[8];
#pragma unroll
    for (int j = 0; j < 8; ++j) acc[j] = (v2f){0.0f, 0.0f};

    // ---- L0: load AND consume the x-part BEFORE the wait (local data) ----
    if (active && L == 0) {
      v2f xa[4], xb[4];
      const float* xp = xT + (size_t)t * (II * BB);
      loadx2<4>(xp, kseg * 8,     bp, xa);
      loadx2<4>(xp, kseg * 8 + 4, bp, xb);
      consume2<4>(wroA, kseg * 8,     xa, acc);
      consume2<4>(wroA, kseg * 8 + 4, xb, acc);
    }

    // ---- wait: all blocks published phase s-1 (u64-packed flag reads) ----
    if (s > 0) {
      if (tid < 64) {
        const unsigned tgt = (unsigned)s;
        const unsigned long long* f64 = (const unsigned long long*)flags;
        for (;;) {
          const unsigned long long a = __hip_atomic_load(f64 + tid,      __ATOMIC_RELAXED, __HIP_MEMORY_SCOPE_AGENT);
          const unsigned long long b = __hip_atomic_load(f64 + tid + 64, __ATOMIC_RELAXED, __HIP_MEMORY_SCOPE_AGENT);
          const unsigned mn = umin2(umin2((unsigned)a, (unsigned)(a >> 32)),
                                    umin2((unsigned)b, (unsigned)(b >> 32)));
          if (__all(mn >= tgt)) break;
          __builtin_amdgcn_s_sleep(1);
        }
      }
      __syncthreads();
      CBAR();   // keep h loads below the spin at IR level
    }

    if (active) {
      if (L == 0) {
        if (!first) {  // B-part: h0[s-1] @ parity (s-1)&1
          span32(h0ring + (size_t)((s - 1) & 1) * (HH * BB),
                 wroB0, kseg * 32, bp, acc);
        }
      } else {
        span32(h0ring + (size_t)((s - 1) & 1) * (HH * BB),
               wroA, kseg * 32, bp, acc);
        if (!first) {  // B-part: h1[s-2] @ parity s&1
          span32(h1ring + (size_t)(s & 1) * (HH * BB),
                 wroB1, kseg * 32, bp, acc);
        }
      }

      // ---- reduce 16 ksegs -> ACTIVATED gates (16-wave parallel) ----
#pragma unroll
      for (int j = 0; j < 8; ++j) {
        const int row = rhalf * 8 + j;
        *(v2f*)(part + ((((size_t)row * 16 + kseg) * 32 + bp) << 1)) = acc[j];
      }
      __syncthreads();
      {
        const int row = tid >> 6;       // = lr = u*4 + q
        const int bb  = tid & 63;
        const int q   = row & 3;
        float g = 0.0f;
#pragma unroll
        for (int ks = 0; ks < 16; ++ks)
          g += part[((((size_t)row * 16 + ks) * 32 + (bb >> 1)) << 1) + (bb & 1)];
        g += bsum[row];
        gates[row * 64 + bb] = (q == 2) ? ftanh(g) : sigm(g);
      }
      __syncthreads();

      if (tid < 128) {  // cell update: 2 batch elems/thread, 64-bit swap
        const int u   = tid >> 5;
        const int bb0 = (tid & 31) << 1, bb1 = bb0 + 1;
        const float gi0 = gates[((u << 2) + 0) * 64 + bb0];
        const float gf0 = gates[((u << 2) + 1) * 64 + bb0];
        const float gg0 = gates[((u << 2) + 2) * 64 + bb0];
        const float go0 = gates[((u << 2) + 3) * 64 + bb0];
        const float gi1 = gates[((u << 2) + 0) * 64 + bb1];
        const float gf1 = gates[((u << 2) + 1) * 64 + bb1];
        const float gg1 = gates[((u << 2) + 2) * 64 + bb1];
        const float go1 = gates[((u << 2) + 3) * 64 + bb1];
        const float c0 = first ? 0.0f : cst[u * 64 + bb0];
        const float c1 = first ? 0.0f : cst[u * 64 + bb1];
        const float cn0 = gf0 * c0 + gi0 * gg0;
        const float cn1 = gf1 * c1 + gi1 * gg1;
        const float hn0 = go0 * ftanh(cn0);
        const float hn1 = go1 * ftanh(cn1);
        cst[u * 64 + bb0] = cn0;
        cst[u * 64 + bb1] = cn1;
        float* hdst = (L ? h1ring : h0ring) + (size_t)(t & 1) * (HH * BB);
        unsigned long long pk =
            (unsigned long long)__float_as_uint(hn0) |
            ((unsigned long long)__float_as_uint(hn1) << 32);
        // 64-bit swap-with-return: performed AT the MALL; asm sink forces
        // the s_waitcnt on the return before the barrier below (r16-proven).
        unsigned long long old = __hip_atomic_exchange(
            (unsigned long long*)(hdst + (ub + u) * 64 + bb0), pk,
            __ATOMIC_RELAXED, __HIP_MEMORY_SCOPE_AGENT);
        asm volatile("" :: "v"(old));
      }
    }

    // all swaps' returns received (h at MALL) before any thread passes here;
    // the flag store is issued strictly afterwards -> cannot be seen early.
    __syncthreads();
    if (tid == 0 && s < TT) {   // last phase: nobody consumes the flag
      __hip_atomic_store(flags + bid, (unsigned)(s + 1),
                         __ATOMIC_RELAXED, __HIP_MEMORY_SCOPE_AGENT);
    }
  }
}

// ---------------------------------------------------------------------------
// out[b] = sum_j h1_last[j][b] * Wl[j] + bl[0]
// ---------------------------------------------------------------------------
__global__ __launch_bounds__(512) void k_final(const float* __restrict__ h1last,
                                               const float* __restrict__ Wl,
                                               const float* __restrict__ bl,
                                               float* __restrict__ out) {
  __shared__ float red[8][64];
  const int jg = threadIdx.x >> 6, b = threadIdx.x & 63;
  float a = 0.0f;
  for (int jj = 0; jj < 64; ++jj) {
    const int j = (jg << 6) + jj;
    a += h1last[j * BB + b] * Wl[j];
  }
  red[jg][b] = a;
  __syncthreads();
  if (threadIdx.x < 64) {
    float s = bl[0];
#pragma unroll
    for (int g = 0; g < 8; ++g) s += red[g][threadIdx.x];
    out[threadIdx.x] = s;
  }
}

extern "C" void kernel_launch(void* const* d_in, const int* in_sizes, int n_in,
                              void* d_out, int out_size, void* d_ws, size_t ws_size,
                              hipStream_t stream) {
  (void)in_sizes; (void)n_in; (void)out_size; (void)ws_size;
  const float* x     = (const float*)d_in[0];
  const float* W_ih0 = (const float*)d_in[1];
  const float* W_hh0 = (const float*)d_in[2];
  const float* b_ih0 = (const float*)d_in[3];
  const float* b_hh0 = (const float*)d_in[4];
  const float* W_ih1 = (const float*)d_in[5];
  const float* W_hh1 = (const float*)d_in[6];
  const float* b_ih1 = (const float*)d_in[7];
  const float* b_hh1 = (const float*)d_in[8];
  const float* Wl    = (const float*)d_in[9];
  const float* bl    = (const float*)d_in[10];
  float* out = (float*)d_out;

  float* ws       = (float*)d_ws;
  float* xT       = ws;                         // 512*128*64
  float* h0ring   = xT + (size_t)TT * II * BB;  // 2*512*64
  float* h1ring   = h0ring + 2 * HH * BB;       // 2*512*64
  unsigned* flags = (unsigned*)(h1ring + 2 * HH * BB);  // 256 u32 (8B aligned)

  k_transpose_x<<<1024, 1024, 0, stream>>>(x, xT);
  k_init_flags<<<1, NBLK, 0, stream>>>(flags);

  hipFuncSetAttribute((const void*)k_lstm_persist,
                      hipFuncAttributeMaxDynamicSharedMemorySize, SMEM_BYTES);

  void* args[] = {
    (void*)&xT,
    (void*)&W_ih0, (void*)&W_hh0, (void*)&b_ih0, (void*)&b_hh0,
    (void*)&W_ih1, (void*)&W_hh1, (void*)&b_ih1, (void*)&b_hh1,
    (void*)&h0ring, (void*)&h1ring, (void*)&flags,
  };
  // Cooperative launch kept ONLY for the co-residency guarantee; sync is ours.
  hipLaunchCooperativeKernel((void*)k_lstm_persist, dim3(NBLK), dim3(1024),
                             args, SMEM_BYTES, stream);

  // h1[T-1] lives at ring parity (T-1)&1 == 1
  k_final<<<1, 512, 0, stream>>>(h1ring + HH * BB, Wl, bl, out);
}